// Round 3
// baseline (191.467 us; speedup 1.0000x reference)
//
#include <hip/hip_runtime.h>
#include <hip/hip_bf16.h>
#include <stdint.h>
#include <stddef.h>

typedef __bf16 bf16;
typedef __attribute__((ext_vector_type(8))) __bf16 bf16x8;
typedef __attribute__((ext_vector_type(4))) __bf16 bf16x4;
typedef __attribute__((ext_vector_type(2))) __bf16 bf16x2;
typedef __attribute__((ext_vector_type(4))) float f32x4;

#define MFMA16(a, b, c) __builtin_amdgcn_mfma_f32_16x16x32_bf16(a, b, c, 0, 0, 0)

#define BB 2
#define SEQ 2048
#define FDIM 1024
#define NH 16
#define HD 64
#define M_TOK 4096   /* BB*SEQ */
#define N_QKV 3072   /* 3*FDIM */

#define CSC 0.04508422f  /* (1/32) * log2(e) — folded into Wq/bq */

// async global->LDS, 16B per lane; LDS dest is wave-uniform base + lane*16
__device__ __forceinline__ void gll16(const bf16* g, bf16* l) {
    __builtin_amdgcn_global_load_lds(
        (const __attribute__((address_space(1))) void*)g,
        (__attribute__((address_space(3))) void*)l, 16, 0, 0);
}

// fast f32 -> bf16 (round-to-nearest; 2 VALU ops)
__device__ __forceinline__ bf16 pack_bf16(float f) {
    uint32_t u = __builtin_bit_cast(uint32_t, f);
    uint16_t h = (uint16_t)((u + 0x8000u) >> 16);
    return __builtin_bit_cast(bf16, h);
}

// pack two f32 -> one dword of two bf16 (lo=a, hi=b)
__device__ __forceinline__ uint32_t pk2(float a, float b) {
#if __has_builtin(__builtin_amdgcn_cvt_pk_bf16_f32)
    bf16x2 t = __builtin_amdgcn_cvt_pk_bf16_f32(a, b);
    return __builtin_bit_cast(uint32_t, t);
#else
    uint32_t ua = __builtin_bit_cast(uint32_t, a) + 0x8000u;
    uint32_t ub = __builtin_bit_cast(uint32_t, b) + 0x8000u;
    return __builtin_amdgcn_perm(ub, ua, 0x07060302);
#endif
}

// ---------------------------------------------------------------------------
// fp32 -> bf16 conversion; Wq/bq pre-scaled by CSC.
// ---------------------------------------------------------------------------
__global__ __launch_bounds__(256) void convert_k(
    const float* __restrict__ x,
    const float* __restrict__ Wq, const float* __restrict__ bq,
    const float* __restrict__ Wk, const float* __restrict__ bk,
    const float* __restrict__ Wv, const float* __restrict__ bv,
    const float* __restrict__ Wo,
    bf16* __restrict__ xb, bf16* __restrict__ Wcat, bf16* __restrict__ Wob,
    float* __restrict__ bcat)
{
    const int tid = blockIdx.x * blockDim.x + threadIdx.x;
    const int nt = gridDim.x * blockDim.x;
    const int NX4 = M_TOK * FDIM / 4;
    const int NW4 = FDIM * FDIM / 4;

    for (int i = tid; i < NX4; i += nt) {
        float4 v = ((const float4*)x)[i];
        bf16x4 o; o[0] = (bf16)v.x; o[1] = (bf16)v.y; o[2] = (bf16)v.z; o[3] = (bf16)v.w;
        ((bf16x4*)xb)[i] = o;
    }
    for (int i = tid; i < NW4; i += nt) {
        float4 v = ((const float4*)Wq)[i];
        bf16x4 o;
        o[0] = (bf16)(v.x * CSC); o[1] = (bf16)(v.y * CSC);
        o[2] = (bf16)(v.z * CSC); o[3] = (bf16)(v.w * CSC);
        ((bf16x4*)Wcat)[i] = o;
        v = ((const float4*)Wk)[i];
        o[0] = (bf16)v.x; o[1] = (bf16)v.y; o[2] = (bf16)v.z; o[3] = (bf16)v.w;
        ((bf16x4*)Wcat)[NW4 + i] = o;
        v = ((const float4*)Wv)[i];
        o[0] = (bf16)v.x; o[1] = (bf16)v.y; o[2] = (bf16)v.z; o[3] = (bf16)v.w;
        ((bf16x4*)Wcat)[2 * NW4 + i] = o;
        v = ((const float4*)Wo)[i];
        o[0] = (bf16)v.x; o[1] = (bf16)v.y; o[2] = (bf16)v.z; o[3] = (bf16)v.w;
        ((bf16x4*)Wob)[i] = o;
    }
    for (int i = tid; i < FDIM; i += nt) {
        bcat[i] = bq[i] * CSC;
        bcat[FDIM + i] = bk[i];
        bcat[2 * FDIM + i] = bv[i];
    }
}

// ---------------------------------------------------------------------------
// gemm8: C[M,N] = A[M,K] @ B[N,K]^T + bias[N].  8-phase-style schedule
// (T2+T3+T4+T5): BM=256 x BN=128 x BK=64, 8 waves (2M x 4N, 128x32 out/wave),
// ring-3 LDS K-tile buffers (144 KB dynamic LDS, 1 block/CU).
//   - compute K-tile t from slot t%3 while staging t+2 into slot (t+2)%3:
//     prefetch distance 2 with NO write-after-read hazard (slot t+2 was last
//     read at K-tile t-1, finished before t began).
//   - counted s_waitcnt vmcnt(6) at K-tile boundary (6 = t+2's in-flight
//     loads) guarantees t+1 landed; never drains to 0 in the main loop.
//   - T2 LDS swizzle: 16B-slot ^= (row&7); gll16 dest stays LINEAR, the
//     inverse swizzle is applied to the per-lane GLOBAL source address
//     (rule 21), reads use the swizzled address -> no same-bank column.
//   - 2 phases/K-tile: {ds_read 8..12 x b128 | stage 3 gll16 | s_barrier |
//     lgkmcnt(0)+sched_barrier | setprio(1) 16 MFMA setprio(0) |
//     [vmcnt] | s_barrier}.
// VtOut path (n0>=2048): V written transposed+j-permuted as before.
// ---------------------------------------------------------------------------
__global__ __launch_bounds__(512, 2) void gemm8(
    const bf16* __restrict__ A,    // M x K
    const bf16* __restrict__ Bw,   // N x K
    const float* __restrict__ bias,// N
    bf16* __restrict__ Cb,         // bf16 out (or null)
    float* __restrict__ Cf,        // fp32 out (or null)
    bf16* __restrict__ VtOut,      // optional transposed-V output
    int M, int N, int K)
{
    extern __shared__ char smem[];          // 3 * (32KB A + 16KB B) = 144 KB
    const int tid = threadIdx.x;
    const int lane = tid & 63;
    const int wave = tid >> 6;              // 0..7
    const int wr = wave >> 2;               // 0..1 : rows [wr*128, +128)
    const int wc = wave & 3;                // 0..3 : cols [wc*32, +32)
    const int m0 = blockIdx.y * 256;
    const int n0 = blockIdx.x * 128;
    const int lrow = lane & 15;
    const int quad = lane >> 4;
    const int NT = K >> 6;                  // K-tiles of 64

    // ---- staging constants (linear LDS dest, inverse-swizzled global src)
    // phys byte p = c*8192 + wave*1024 + lane*16  ->  prow = c*64 + wave*8
    // + (lane>>3), pslot = lane&7; source k-slot = pslot ^ (prow&7)
    // = (lane&7) ^ (lane>>3)  (per-thread constant).
    const int strow = wave * 8 + (lane >> 3);
    const int koff = (((lane & 7) ^ (lane >> 3)) << 3);
    const bf16* agp = A + (size_t)(m0 + strow) * K + koff;
    const bf16* bgp = Bw + (size_t)(n0 + strow) * K + koff;
    const int swo = wave * 1024;            // wave-uniform LDS byte offset

    // ---- read-side byte offsets (swizzled): byte = row*128 +
    // ((ks*4+quad)^(row&7))*16 ; row&7 == lrow&7 for all frag rows.
    const int axrow = (wr * 128 + lrow) * 128;
    const int bxrow = (wc * 32 + lrow) * 128;
    const int soff0 = ((quad) ^ (lrow & 7)) * 16;
    const int soff1 = ((4 + quad) ^ (lrow & 7)) * 16;

    f32x4 acc[8][2] = {};

#define STAGE_A(slot, kt, c) \
    gll16(agp + (size_t)(c) * 64 * K + (size_t)(kt) * 64, \
          (bf16*)(smem + (slot) * 49152 + (c) * 8192 + swo))
#define STAGE_B(slot, kt, c) \
    gll16(bgp + (size_t)(c) * 64 * K + (size_t)(kt) * 64, \
          (bf16*)(smem + (slot) * 49152 + 32768 + (c) * 8192 + swo))

    // prologue: stage K-tiles 0 (slot 0) and 1 (slot 1); wait tile 0 only.
    STAGE_A(0, 0, 0); STAGE_A(0, 0, 1); STAGE_A(0, 0, 2); STAGE_A(0, 0, 3);
    STAGE_B(0, 0, 0); STAGE_B(0, 0, 1);
    if (NT > 1) {
        STAGE_A(1, 1, 0); STAGE_A(1, 1, 1); STAGE_A(1, 1, 2); STAGE_A(1, 1, 3);
        STAGE_B(1, 1, 0); STAGE_B(1, 1, 1);
    }
    asm volatile("s_waitcnt vmcnt(6)" ::: "memory");
    __builtin_amdgcn_s_barrier();

    int cur = 0;
    for (int t = 0; t < NT; ++t) {
        const int s2 = (cur >= 1) ? cur - 1 : cur + 2;   // (cur+2)%3
        const char* sA = smem + cur * 49152;
        const char* sB = sA + 32768;
        const bool pf = (t + 2 < NT);
        bf16x8 bfr[2][2];

#pragma unroll
        for (int ph = 0; ph < 2; ++ph) {
            bf16x8 af[4][2];
            if (ph == 0) {
#pragma unroll
                for (int j = 0; j < 2; ++j) {
                    bfr[j][0] = *(const bf16x8*)(sB + bxrow + j * 2048 + soff0);
                    bfr[j][1] = *(const bf16x8*)(sB + bxrow + j * 2048 + soff1);
                }
            }
#pragma unroll
            for (int i2 = 0; i2 < 4; ++i2) {
                af[i2][0] = *(const bf16x8*)(sA + axrow + (ph * 4 + i2) * 2048 + soff0);
                af[i2][1] = *(const bf16x8*)(sA + axrow + (ph * 4 + i2) * 2048 + soff1);
            }
            if (pf) {
                if (ph == 0) {
                    STAGE_A(s2, t + 2, 0); STAGE_A(s2, t + 2, 1); STAGE_A(s2, t + 2, 2);
                } else {
                    STAGE_A(s2, t + 2, 3); STAGE_B(s2, t + 2, 0); STAGE_B(s2, t + 2, 1);
                }
            }
            __builtin_amdgcn_s_barrier();
            asm volatile("s_waitcnt lgkmcnt(0)" ::: "memory");
            __builtin_amdgcn_sched_barrier(0);
            __builtin_amdgcn_s_setprio(1);
#pragma unroll
            for (int i2 = 0; i2 < 4; ++i2)
#pragma unroll
                for (int j = 0; j < 2; ++j) {
                    acc[ph * 4 + i2][j] = MFMA16(af[i2][0], bfr[j][0], acc[ph * 4 + i2][j]);
                    acc[ph * 4 + i2][j] = MFMA16(af[i2][1], bfr[j][1], acc[ph * 4 + i2][j]);
                }
            __builtin_amdgcn_s_setprio(0);
            if (ph == 1) {
                if (pf) asm volatile("s_waitcnt vmcnt(6)" ::: "memory");
                else    asm volatile("s_waitcnt vmcnt(0)" ::: "memory");
            }
            __builtin_amdgcn_s_barrier();
        }
        cur = (cur + 1 == 3) ? 0 : cur + 1;
    }
#undef STAGE_A
#undef STAGE_B

    // epilogue: C/D layout col=lane&15, row=(lane>>4)*4+reg  [m89/m91]
    const int r0 = quad * 4;
    if (VtOut && n0 >= 2048) {
        const int bql = (m0 >> 11);            // batch (block-uniform)
#pragma unroll
        for (int i = 0; i < 8; ++i) {
#pragma unroll
            for (int j = 0; j < 2; ++j) {
                const int col = n0 + wc * 32 + j * 16 + lrow;   // 2048..3071
                const float bsv = bias[col];
                const int vh = col - 2048;                 // h*64 + d
                const int row = m0 + wr * 128 + i * 16 + r0;   // token of reg 0
                const int jj = row & (SEQ - 1);
                const int g = jj & 63;
                const int jj2 = (jj & ~63) | ((g >> 5) << 5)
                              | (((g >> 2) & 3) << 3) | (((g >> 4) & 1) << 2);
                bf16x4 vv;
#pragma unroll
                for (int r = 0; r < 4; ++r)
                    vv[r] = pack_bf16(acc[i][j][r] + bsv);
                *(bf16x4*)&VtOut[((size_t)bql * 16 * 64 + vh) * SEQ + jj2] = vv;
            }
        }
        return;
    }
#pragma unroll
    for (int i = 0; i < 8; ++i) {
#pragma unroll
        for (int j = 0; j < 2; ++j) {
            const int col = n0 + wc * 32 + j * 16 + lrow;
            const float bsv = bias[col];
#pragma unroll
            for (int r = 0; r < 4; ++r) {
                const int row = m0 + wr * 128 + i * 16 + r0 + r;
                const float v = acc[i][j][r] + bsv;
                if (Cb) Cb[(size_t)row * N + col] = pack_bf16(v);
                else    Cf[(size_t)row * N + col] = v;
            }
        }
    }
}

// ---------------------------------------------------------------------------
// Flash attention v8: 8-wave blocks = 4 q-groups x 2 j-parities.
// (unchanged from round 2: Occ 31%, 45.2 us)
// ---------------------------------------------------------------------------
__global__ __launch_bounds__(512, 4) void attn_k(
    const bf16* __restrict__ QKV,  // M_TOK x 3072 : [Q | K | (unused V)]
    const bf16* __restrict__ Vt,   // [bh*64 + d][SEQ], j-permuted per 64-tile
    bf16* __restrict__ O)          // M_TOK x 1024
{
    const int bx = blockIdx.x;
    const int bh = (bx & 7) + 8 * ((bx >> 3) & 3);   // same bh -> same XCD (%8)
    const int qblk = bx >> 5;
    const int b = bh >> 4;
    const int h = bh & 15;
    const int lane = threadIdx.x & 63;
    const int wave = threadIdx.x >> 6;   // 0..7
    const int qg = wave & 3;             // q-group (32 rows each)
    const int jp = wave >> 2;            // j-chunk parity
    const int lrow = lane & 15;
    const int quad = lane >> 4;
    const int lk8 = quad * 8;

    __shared__ __align__(16) bf16 Ks[2][2][128 * 32];  // [stage][ksplit][j<128]
    __shared__ __align__(16) bf16 Vs[2][4][64 * 32];   // [stage][j-32-chunk][d<64]

    const size_t base = (size_t)b * SEQ * N_QKV;
    const bf16* Qp = QKV + base + h * HD;
    const bf16* Kp = QKV + base + FDIM + h * HD;
    const bf16* Vtp = Vt + (size_t)bh * HD * SEQ;

    const int qr0 = qblk * 128 + qg * 32;

    bf16x8 qf[2][2];
#pragma unroll
    for (int qt = 0; qt < 2; ++qt)
#pragma unroll
        for (int ks = 0; ks < 2; ++ks)
            qf[qt][ks] = *(const bf16x8*)(Qp + (size_t)(qr0 + qt * 16 + lrow) * N_QKV
                                          + ks * 32 + lk8);

    bf16x8 ones8;
#pragma unroll
    for (int e = 0; e < 8; ++e) ones8[e] = (bf16)1.0f;

    const f32x4 zf = {0.f, 0.f, 0.f, 0.f};   // persistent zero C operand

    f32x4 o[2][4] = {};   // O^T frags: [qt][df]
    f32x4 o4[2] = {};     // row sums (replicated over rows)

    const int srow = wave * 16 + (lane >> 2);
    const int scol = (lane & 3) * 8;
    const bf16* kg = Kp + (size_t)srow * N_QKV + scol;
    const int vsrow = qg * 16 + (lane >> 2);
    const bf16* vg = Vtp + (size_t)vsrow * SEQ + jp * 32 + scol;
    const int kwo = wave * 512;   // bf16 elems; wave-uniform LDS dest offset

    // prologue: stage j-tile 0 (128 j) into buffer 0
    gll16(kg,      &Ks[0][0][0] + kwo);
    gll16(kg + 32, &Ks[0][1][0] + kwo);
    gll16(vg,      &Vs[0][0][0] + kwo);    // chunks 0,1
    gll16(vg + 64, &Vs[0][2][0] + kwo);    // chunks 2,3
    kg += (size_t)128 * N_QKV;
    vg += 128;

    for (int jt = 0; jt < SEQ / 128; ++jt) {
        const int cur = jt & 1;
        __syncthreads();   // drains loads(jt); all waves done reading buf cur^1

        if (jt + 1 < SEQ / 128) {
            const int nxt = cur ^ 1;
            gll16(kg,      &Ks[nxt][0][0] + kwo);
            gll16(kg + 32, &Ks[nxt][1][0] + kwo);
            gll16(vg,      &Vs[nxt][0][0] + kwo);
            gll16(vg + 64, &Vs[nxt][2][0] + kwo);
            kg += (size_t)128 * N_QKV;
            vg += 128;
        }

        // 128 j = 4 chunks of 32; this wave does chunks {jp, jp+2}
#pragma unroll
        for (int pp = 0; pp < 2; ++pp) {
            const int p = (pp << 1) | jp;
            f32x4 Sp[2][2];   // [m=jn&1][qt]
            __builtin_amdgcn_s_setprio(1);
#pragma unroll
            for (int m = 0; m < 2; ++m) {
                const int jn = 2 * p + m;
                bf16x8 kb0 = *(const bf16x8*)&Ks[cur][0][(jn * 16 + lrow) * 32 + lk8];
                bf16x8 kb1 = *(const bf16x8*)&Ks[cur][1][(jn * 16 + lrow) * 32 + lk8];
                Sp[m][0] = MFMA16(kb0, qf[0][0], zf);
                Sp[m][0] = MFMA16(kb1, qf[0][1], Sp[m][0]);
                Sp[m][1] = MFMA16(kb0, qf[1][0], zf);
                Sp[m][1] = MFMA16(kb1, qf[1][1], Sp[m][1]);
            }
            __builtin_amdgcn_s_setprio(0);

            // P^T = exp2(S^T) packed into K=32 B-frags (perm pi, matches Vt)
            union { bf16x8 v; uint32_t d[4]; } pb[2];
#pragma unroll
            for (int qt = 0; qt < 2; ++qt) {
                const f32x4 s0 = Sp[0][qt];
                const f32x4 s1 = Sp[1][qt];
                pb[qt].d[0] = pk2(__builtin_amdgcn_exp2f(s0[0]),
                                  __builtin_amdgcn_exp2f(s0[1]));
                pb[qt].d[1] = pk2(__builtin_amdgcn_exp2f(s0[2]),
                                  __builtin_amdgcn_exp2f(s0[3]));
                pb[qt].d[2] = pk2(__builtin_amdgcn_exp2f(s1[0]),
                                  __builtin_amdgcn_exp2f(s1[1]));
                pb[qt].d[3] = pk2(__builtin_amdgcn_exp2f(s1[2]),
                                  __builtin_amdgcn_exp2f(s1[3]));
            }

            __builtin_amdgcn_s_setprio(1);
            o4[0] = MFMA16(ones8, pb[0].v, o4[0]);
            o4[1] = MFMA16(ones8, pb[1].v, o4[1]);
#pragma unroll
            for (int df = 0; df < 4; ++df) {
                bf16x8 vA = *(const bf16x8*)&Vs[cur][p][(df * 16 + lrow) * 32 + lk8];
                o[0][df] = MFMA16(vA, pb[0].v, o[0][df]);
                o[1][df] = MFMA16(vA, pb[1].v, o[1][df]);
            }
            __builtin_amdgcn_s_setprio(0);
        }
    }

    // combine j-parity partials through LDS (safe to overwrite Ks/Vs now)
    __syncthreads();
    float* shO = (float*)Ks;   // [qt*4+df][qg][lane] f32x4
    float* shS = (float*)Vs;   // rowsum partials
    if (jp == 1) {
#pragma unroll
        for (int qt = 0; qt < 2; ++qt)
#pragma unroll
            for (int df = 0; df < 4; ++df)
                *(f32x4*)&shO[((((qt * 4 + df) * 4) + qg) * 64 + lane) * 4] = o[qt][df];
        shS[(qg * 64 + lane) * 2 + 0] = o4[0][0];
        shS[(qg * 64 + lane) * 2 + 1] = o4[1][0];
    }
    __syncthreads();
    if (jp == 1) return;

#pragma unroll
    for (int qt = 0; qt < 2; ++qt)
#pragma unroll
        for (int df = 0; df < 4; ++df) {
            f32x4 t = *(const f32x4*)&shO[((((qt * 4 + df) * 4) + qg) * 64 + lane) * 4];
            o[qt][df][0] += t[0]; o[qt][df][1] += t[1];
            o[qt][df][2] += t[2]; o[qt][df][3] += t[3];
        }
    const float den0 = o4[0][0] + shS[(qg * 64 + lane) * 2 + 0];
    const float den1 = o4[1][0] + shS[(qg * 64 + lane) * 2 + 1];

    // epilogue: O^T frag: d = df*16 + quad*4 + r, q = lane&15
#pragma unroll
    for (int qt = 0; qt < 2; ++qt) {
        const float inv = 1.0f / (qt ? den1 : den0);
        const int q = qr0 + qt * 16 + lrow;
#pragma unroll
        for (int df = 0; df < 4; ++df) {
            bf16x4 vv;
#pragma unroll
            for (int r = 0; r < 4; ++r)
                vv[r] = pack_bf16(o[qt][df][r] * inv);
            *(bf16x4*)&O[(size_t)(b * SEQ + q) * FDIM + h * HD + df * 16 + quad * 4] = vv;
        }
    }
}

// ---------------------------------------------------------------------------
extern "C" void kernel_launch(void* const* d_in, const int* in_sizes, int n_in,
                              void* d_out, int out_size, void* d_ws, size_t ws_size,
                              hipStream_t stream) {
    (void)in_sizes; (void)n_in; (void)out_size; (void)ws_size;
    const float* x  = (const float*)d_in[0];
    const float* Wq = (const float*)d_in[1];
    const float* bq = (const float*)d_in[2];
    const float* Wk = (const float*)d_in[3];
    const float* bk = (const float*)d_in[4];
    const float* Wv = (const float*)d_in[5];
    const float* bv = (const float*)d_in[6];
    const float* Wo = (const float*)d_in[7];
    const float* bo = (const float*)d_in[8];
    float* out = (float*)d_out;

    char* ws = (char*)d_ws;
    bf16* xb    = (bf16*)(ws);                // 8 MB; reused as Ob after GEMM1
    bf16* Wcat  = (bf16*)(ws + 8388608);      // 6 MB
    bf16* Wob   = (bf16*)(ws + 14680064);     // 2 MB
    float* bcat = (float*)(ws + 16777216);    // 12 KB
    bf16* QKV   = (bf16*)(ws + 16789504);     // 24 MB (V third unused)
    bf16* Vt    = (bf16*)(ws + 41955328);     // 8 MB, j-permuted layout
    bf16* Ob    = xb;                         // x no longer needed after GEMM1

    static bool s_attr_done = false;
    if (!s_attr_done) {
        (void)hipFuncSetAttribute(reinterpret_cast<const void*>(gemm8),
                                  hipFuncAttributeMaxDynamicSharedMemorySize,
                                  147456);
        s_attr_done = true;
    }

    convert_k<<<dim3(1024), dim3(256), 0, stream>>>(x, Wq, bq, Wk, bk, Wv, bv, Wo,
                                                    xb, Wcat, Wob, bcat);
    gemm8<<<dim3(N_QKV / 128, M_TOK / 256), dim3(512), 147456, stream>>>(
        xb, Wcat, bcat, QKV, nullptr, Vt, M_TOK, N_QKV, FDIM);
    attn_k<<<dim3((SEQ / 128) * BB * NH), dim3(512), 0, stream>>>(QKV, Vt, Ob);
    gemm8<<<dim3(FDIM / 128, M_TOK / 256), dim3(512), 147456, stream>>>(
        Ob, Wob, bo, nullptr, out, nullptr, M_TOK, FDIM, FDIM);
}

// Round 4
// 183.308 us; speedup vs baseline: 1.0445x; 1.0445x over previous
//
#include <hip/hip_runtime.h>
#include <hip/hip_bf16.h>
#include <stdint.h>
#include <stddef.h>

typedef __bf16 bf16;
typedef __attribute__((ext_vector_type(8))) __bf16 bf16x8;
typedef __attribute__((ext_vector_type(4))) __bf16 bf16x4;
typedef __attribute__((ext_vector_type(2))) __bf16 bf16x2;
typedef __attribute__((ext_vector_type(4))) float f32x4;

#define MFMA16(a, b, c) __builtin_amdgcn_mfma_f32_16x16x32_bf16(a, b, c, 0, 0, 0)

#define BB 2
#define SEQ 2048
#define FDIM 1024
#define NH 16
#define HD 64
#define M_TOK 4096   /* BB*SEQ */
#define N_QKV 3072   /* 3*FDIM */

#define CSC 0.04508422f  /* (1/32) * log2(e) — folded into Wq/bq */

// async global->LDS, 16B per lane; LDS dest is wave-uniform base + lane*16
__device__ __forceinline__ void gll16(const bf16* g, bf16* l) {
    __builtin_amdgcn_global_load_lds(
        (const __attribute__((address_space(1))) void*)g,
        (__attribute__((address_space(3))) void*)l, 16, 0, 0);
}

// fast f32 -> bf16 (round-to-nearest; 2 VALU ops)
__device__ __forceinline__ bf16 pack_bf16(float f) {
    uint32_t u = __builtin_bit_cast(uint32_t, f);
    uint16_t h = (uint16_t)((u + 0x8000u) >> 16);
    return __builtin_bit_cast(bf16, h);
}

// pack two f32 -> one dword of two bf16 (lo=a, hi=b)
__device__ __forceinline__ uint32_t pk2(float a, float b) {
#if __has_builtin(__builtin_amdgcn_cvt_pk_bf16_f32)
    bf16x2 t = __builtin_amdgcn_cvt_pk_bf16_f32(a, b);
    return __builtin_bit_cast(uint32_t, t);
#else
    uint32_t ua = __builtin_bit_cast(uint32_t, a) + 0x8000u;
    uint32_t ub = __builtin_bit_cast(uint32_t, b) + 0x8000u;
    return __builtin_amdgcn_perm(ub, ua, 0x07060302);
#endif
}

// ---------------------------------------------------------------------------
// fp32 -> bf16 conversion; Wq/bq pre-scaled by CSC.
// ---------------------------------------------------------------------------
__global__ __launch_bounds__(256) void convert_k(
    const float* __restrict__ x,
    const float* __restrict__ Wq, const float* __restrict__ bq,
    const float* __restrict__ Wk, const float* __restrict__ bk,
    const float* __restrict__ Wv, const float* __restrict__ bv,
    const float* __restrict__ Wo,
    bf16* __restrict__ xb, bf16* __restrict__ Wcat, bf16* __restrict__ Wob,
    float* __restrict__ bcat)
{
    const int tid = blockIdx.x * blockDim.x + threadIdx.x;
    const int nt = gridDim.x * blockDim.x;
    const int NX4 = M_TOK * FDIM / 4;
    const int NW4 = FDIM * FDIM / 4;

    for (int i = tid; i < NX4; i += nt) {
        float4 v = ((const float4*)x)[i];
        bf16x4 o; o[0] = (bf16)v.x; o[1] = (bf16)v.y; o[2] = (bf16)v.z; o[3] = (bf16)v.w;
        ((bf16x4*)xb)[i] = o;
    }
    for (int i = tid; i < NW4; i += nt) {
        float4 v = ((const float4*)Wq)[i];
        bf16x4 o;
        o[0] = (bf16)(v.x * CSC); o[1] = (bf16)(v.y * CSC);
        o[2] = (bf16)(v.z * CSC); o[3] = (bf16)(v.w * CSC);
        ((bf16x4*)Wcat)[i] = o;
        v = ((const float4*)Wk)[i];
        o[0] = (bf16)v.x; o[1] = (bf16)v.y; o[2] = (bf16)v.z; o[3] = (bf16)v.w;
        ((bf16x4*)Wcat)[NW4 + i] = o;
        v = ((const float4*)Wv)[i];
        o[0] = (bf16)v.x; o[1] = (bf16)v.y; o[2] = (bf16)v.z; o[3] = (bf16)v.w;
        ((bf16x4*)Wcat)[2 * NW4 + i] = o;
        v = ((const float4*)Wo)[i];
        o[0] = (bf16)v.x; o[1] = (bf16)v.y; o[2] = (bf16)v.z; o[3] = (bf16)v.w;
        ((bf16x4*)Wob)[i] = o;
    }
    for (int i = tid; i < FDIM; i += nt) {
        bcat[i] = bq[i] * CSC;
        bcat[FDIM + i] = bk[i];
        bcat[2 * FDIM + i] = bv[i];
    }
}

// ---------------------------------------------------------------------------
// gemm256: C[M,N] = A[M,K] @ B[N,K]^T + bias[N].  m201 geometry:
// BM=BN=256, BK=64, 8 waves (2M x 4N), per-wave 128x64 output.
// 4 phases/K-tile, one (mh,nh) C-quadrant x 16 MFMA each.
//   - LDS 2 slots x 64KB (A 32KB + B 32KB); region layout groups each
//     quadrant's operands contiguously: A rows stored [mh][wr][64r],
//     B cols stored [nh][wc][32c] (bit-permuted rows; source addresses
//     pre-permuted, rule 21).
//   - af cached over the nh-pair (A region read once per mh), B quadrant
//     cached over the mh-pair -> 24KB LDS-read per wave per K-tile
//     (192KB/block vs 614cyc MFMA: ~82% pipe ceiling).
//   - stage 1 region (2 gll16/wave) per phase into the other slot; regions
//     of that slot are all dead (read >=2 barriers earlier).  Uniform
//     counted vmcnt(4) gate per phase (exactly 4 younger loads at each
//     region's first use); never drains to 0 in steady state (T4).
//   - T2 XOR swizzle on 16B k-slots (slot ^= row&7), inverse applied to
//     the global source k-offset; read side applies the same XOR.
//   - one s_barrier per phase; setprio(1) around the MFMA cluster (T5).
// VtOut path (n0>=2048): V written transposed+j-permuted for attn.
// ---------------------------------------------------------------------------
__global__ __launch_bounds__(512, 2) void gemm256(
    const bf16* __restrict__ A,    // M x K
    const bf16* __restrict__ Bw,   // N x K
    const float* __restrict__ bias,// N
    bf16* __restrict__ Cb,         // bf16 out
    bf16* __restrict__ VtOut,      // optional transposed-V output
    int M, int N, int K)
{
    extern __shared__ char smem[];          // 2 x 65536 = 131072
    const int tid = threadIdx.x;
    const int lane = tid & 63;
    const int wave = tid >> 6;              // 0..7
    const int wr = wave >> 2;               // 0..1
    const int wc = wave & 3;                // 0..3
    const int m0 = blockIdx.y * 256;
    const int n0 = blockIdx.x * 256;
    const int lrow = lane & 15;
    const int quad = lane >> 4;
    const int NT = K >> 6;

    // staging: region = 16KB = 128 perm'd rows x 64 k; wave w call c covers
    // rows 8*(2w+c).. +7; lane -> row +(lane>>3), phys 16B slot lane&7;
    // stored logical k-slot = (lane&7)^(lane>>3)  (XOR swizzle, rule 21).
    const int l8 = lane >> 3;
    const int kx = ((lane & 7) ^ l8) << 3;  // source k element offset
    const int lcl = wave * 16 + l8;

#define ASTG(sl, kt, mh, c) do { \
    const int _lc = lcl + (c) * 8; \
    const int _gr = m0 + ((_lc >> 6) << 7) + ((mh) << 6) + (_lc & 63); \
    gll16(A + (size_t)_gr * K + (size_t)(kt) * 64 + kx, \
          (bf16*)(smem + (sl) * 65536 + (mh) * 16384 + wave * 2048 + (c) * 1024)); \
} while (0)
#define BSTG(sl, kt, nh, c) do { \
    const int _lc = lcl + (c) * 8; \
    const int _gc = n0 + ((_lc >> 5) << 6) + ((nh) << 5) + (_lc & 31); \
    gll16(Bw + (size_t)_gc * K + (size_t)(kt) * 64 + kx, \
          (bf16*)(smem + (sl) * 65536 + 32768 + (nh) * 16384 + wave * 2048 + (c) * 1024)); \
} while (0)

    // read-side: swizzled 16B slot = (ks*4+quad) ^ (row&7); row&7 == lrow&7
    const int swz0 = ((quad ^ (lrow & 7)) << 4);
    const int swz1 = (((4 + quad) ^ (lrow & 7)) << 4);
    const int arow = (wr * 64 + lrow) * 128;
    const int brow = (wc * 32 + lrow) * 128;

    f32x4 acc[8][4] = {};
    bf16x8 af[4][2];        // [iq][ks], cached across each nh-pair
    bf16x8 bc[2][2][2];     // [nh][jq][ks], cached across the mh-pair

    // prologue: stage tile 0 (order A0,B0,B1,A1), gate first two regions
    ASTG(0, 0, 0, 0); ASTG(0, 0, 0, 1);
    BSTG(0, 0, 0, 0); BSTG(0, 0, 0, 1);
    BSTG(0, 0, 1, 0); BSTG(0, 0, 1, 1);
    ASTG(0, 0, 1, 0); ASTG(0, 0, 1, 1);
    asm volatile("s_waitcnt vmcnt(4)" ::: "memory");
    __builtin_amdgcn_s_barrier();

    for (int t = 0; t < NT; ++t) {
        const int sl = t & 1;
        const int ns = sl ^ 1;
        const char* sb = smem + sl * 65536;
        const bool pf = (t + 1 < NT);

#pragma unroll
        for (int ph = 0; ph < 4; ++ph) {
            const int mh = ph >> 1, nh = ph & 1;
            // stage one region of tile t+1 (schedule: A0,B0,B1,A1)
            if (pf) {
                if (ph == 0)      { ASTG(ns, t + 1, 0, 0); ASTG(ns, t + 1, 0, 1); }
                else if (ph == 1) { BSTG(ns, t + 1, 0, 0); BSTG(ns, t + 1, 0, 1); }
                else if (ph == 2) { BSTG(ns, t + 1, 1, 0); BSTG(ns, t + 1, 1, 1); }
                else              { ASTG(ns, t + 1, 1, 0); ASTG(ns, t + 1, 1, 1); }
            }
            if (nh == 0) {      // first phase of mh-pair: read A quadrant
#pragma unroll
                for (int iq = 0; iq < 4; ++iq) {
                    af[iq][0] = *(const bf16x8*)(sb + mh * 16384 + arow + iq * 2048 + swz0);
                    af[iq][1] = *(const bf16x8*)(sb + mh * 16384 + arow + iq * 2048 + swz1);
                }
            }
            if (ph == 0 || ph == 1) {   // first use of nh: read B quadrant
#pragma unroll
                for (int jq = 0; jq < 2; ++jq) {
                    bc[nh][jq][0] = *(const bf16x8*)(sb + 32768 + nh * 16384 + brow + jq * 2048 + swz0);
                    bc[nh][jq][1] = *(const bf16x8*)(sb + 32768 + nh * 16384 + brow + jq * 2048 + swz1);
                }
            }
            __builtin_amdgcn_s_setprio(1);
#pragma unroll
            for (int iq = 0; iq < 4; ++iq)
#pragma unroll
                for (int jq = 0; jq < 2; ++jq) {
                    acc[mh * 4 + iq][nh * 2 + jq] =
                        MFMA16(af[iq][0], bc[nh][jq][0], acc[mh * 4 + iq][nh * 2 + jq]);
                    acc[mh * 4 + iq][nh * 2 + jq] =
                        MFMA16(af[iq][1], bc[nh][jq][1], acc[mh * 4 + iq][nh * 2 + jq]);
                }
            __builtin_amdgcn_s_setprio(0);
            if (pf) asm volatile("s_waitcnt vmcnt(4)" ::: "memory");
            else    asm volatile("s_waitcnt vmcnt(0)" ::: "memory");
            __builtin_amdgcn_s_barrier();
        }
    }
#undef ASTG
#undef BSTG

    // epilogue: C/D layout col=lane&15, row=(lane>>4)*4+reg  [m89/m91]
    // i = mh*4+iq -> row = m0 + wr*128 + (i>>2)*64 + (i&3)*16 + quad*4 + r
    // j = nh*2+jq -> col = n0 + wc*64 + (j>>1)*32 + (j&1)*16 + lrow
    if (VtOut && n0 >= 2048) {
        const int bql = (m0 >> 11);
#pragma unroll
        for (int i = 0; i < 8; ++i) {
#pragma unroll
            for (int j = 0; j < 4; ++j) {
                const int col = n0 + wc * 64 + (j >> 1) * 32 + (j & 1) * 16 + lrow;
                const float bsv = bias[col];
                const int vh = col - 2048;
                const int row = m0 + wr * 128 + (i >> 2) * 64 + (i & 3) * 16 + quad * 4;
                const int jj = row & (SEQ - 1);
                const int g = jj & 63;
                const int jj2 = (jj & ~63) | ((g >> 5) << 5)
                              | (((g >> 2) & 3) << 3) | (((g >> 4) & 1) << 2);
                bf16x4 vv;
#pragma unroll
                for (int r = 0; r < 4; ++r)
                    vv[r] = pack_bf16(acc[i][j][r] + bsv);
                *(bf16x4*)&VtOut[((size_t)bql * 16 * 64 + vh) * SEQ + jj2] = vv;
            }
        }
        return;
    }
#pragma unroll
    for (int i = 0; i < 8; ++i) {
#pragma unroll
        for (int j = 0; j < 4; ++j) {
            const int col = n0 + wc * 64 + (j >> 1) * 32 + (j & 1) * 16 + lrow;
            const float bsv = bias[col];
#pragma unroll
            for (int r = 0; r < 4; ++r) {
                const int row = m0 + wr * 128 + (i >> 2) * 64 + (i & 3) * 16 + quad * 4 + r;
                Cb[(size_t)row * N + col] = pack_bf16(acc[i][j][r] + bsv);
            }
        }
    }
}

// ---------------------------------------------------------------------------
// gemm_bt<64>: round-2 output-projection GEMM (512 blocks, high occupancy).
// C[M,N] = A[M,K] @ B[N,K]^T + bias[N], fp32 out.
// ---------------------------------------------------------------------------
template<int MT>
__global__ __launch_bounds__(256) void gemm_bt(
    const bf16* __restrict__ A,    // M x K
    const bf16* __restrict__ Bw,   // N x K
    const float* __restrict__ bias,// N
    float* __restrict__ Cf,        // fp32 out
    int M, int N, int K)
{
    constexpr int RI = MT / 32;    // row frags per wave
    __shared__ __align__(16) bf16 As[2][MT * 32];
    __shared__ __align__(16) bf16 Bs[2][128 * 32];

    const int tid = threadIdx.x;
    const int lane = tid & 63;
    const int wave = tid >> 6;
    const int m0 = blockIdx.y * MT;
    const int n0 = blockIdx.x * 128;
    const int wm = (wave >> 1) * (MT / 2);
    const int wn = (wave & 1) * 64;
    const int lrow = lane & 15;
    const int lk8 = (lane >> 4) * 8;

    f32x4 acc[RI][4] = {};

    const int srow = wave * 16 + (lane >> 2);
    const int scol = (lane & 3) * 8;
    const bf16* Ag = A + (size_t)(m0 + srow) * K + scol;
    const bf16* Bg = Bw + (size_t)(n0 + srow) * K + scol;
    const int wo = (wave * 16) * 32;

    gll16(Ag, &As[0][wo]);
    if (MT == 128) gll16(Ag + (size_t)64 * K, &As[0][wo + 2048]);
    gll16(Bg, &Bs[0][wo]);
    gll16(Bg + (size_t)64 * K, &Bs[0][wo + 2048]);

    for (int k0 = 0, it = 0; k0 < K; k0 += 32, ++it) {
        const int cur = it & 1;
        __syncthreads();

        if (k0 + 32 < K) {
            const int nxt = cur ^ 1;
            gll16(Ag + k0 + 32, &As[nxt][wo]);
            if (MT == 128) gll16(Ag + (size_t)64 * K + k0 + 32, &As[nxt][wo + 2048]);
            gll16(Bg + k0 + 32, &Bs[nxt][wo]);
            gll16(Bg + (size_t)64 * K + k0 + 32, &Bs[nxt][wo + 2048]);
        }

        bf16x8 af[RI], bfr[4];
#pragma unroll
        for (int s = 0; s < RI; ++s)
            af[s] = *(const bf16x8*)&As[cur][(wm + s * 16 + lrow) * 32 + lk8];
#pragma unroll
        for (int s = 0; s < 4; ++s)
            bfr[s] = *(const bf16x8*)&Bs[cur][(wn + s * 16 + lrow) * 32 + lk8];
#pragma unroll
        for (int i = 0; i < RI; ++i)
#pragma unroll
            for (int j = 0; j < 4; ++j)
                acc[i][j] = MFMA16(af[i], bfr[j], acc[i][j]);
    }

    const int r0 = (lane >> 4) * 4;
#pragma unroll
    for (int i = 0; i < RI; ++i) {
#pragma unroll
        for (int j = 0; j < 4; ++j) {
            const int col = n0 + wn + j * 16 + lrow;
            const float bsv = bias[col];
#pragma unroll
            for (int r = 0; r < 4; ++r) {
                const int row = m0 + wm + i * 16 + r0 + r;
                Cf[(size_t)row * N + col] = acc[i][j][r] + bsv;
            }
        }
    }
}

// ---------------------------------------------------------------------------
// Flash attention v8: 8-wave blocks = 4 q-groups x 2 j-parities.
// (unchanged from round 2: Occ 31%, 45.2 us)
// ---------------------------------------------------------------------------
__global__ __launch_bounds__(512, 4) void attn_k(
    const bf16* __restrict__ QKV,  // M_TOK x 3072 : [Q | K | (unused V)]
    const bf16* __restrict__ Vt,   // [bh*64 + d][SEQ], j-permuted per 64-tile
    bf16* __restrict__ O)          // M_TOK x 1024
{
    const int bx = blockIdx.x;
    const int bh = (bx & 7) + 8 * ((bx >> 3) & 3);   // same bh -> same XCD (%8)
    const int qblk = bx >> 5;
    const int b = bh >> 4;
    const int h = bh & 15;
    const int lane = threadIdx.x & 63;
    const int wave = threadIdx.x >> 6;   // 0..7
    const int qg = wave & 3;             // q-group (32 rows each)
    const int jp = wave >> 2;            // j-chunk parity
    const int lrow = lane & 15;
    const int quad = lane >> 4;
    const int lk8 = quad * 8;

    __shared__ __align__(16) bf16 Ks[2][2][128 * 32];  // [stage][ksplit][j<128]
    __shared__ __align__(16) bf16 Vs[2][4][64 * 32];   // [stage][j-32-chunk][d<64]

    const size_t base = (size_t)b * SEQ * N_QKV;
    const bf16* Qp = QKV + base + h * HD;
    const bf16* Kp = QKV + base + FDIM + h * HD;
    const bf16* Vtp = Vt + (size_t)bh * HD * SEQ;

    const int qr0 = qblk * 128 + qg * 32;

    bf16x8 qf[2][2];
#pragma unroll
    for (int qt = 0; qt < 2; ++qt)
#pragma unroll
        for (int ks = 0; ks < 2; ++ks)
            qf[qt][ks] = *(const bf16x8*)(Qp + (size_t)(qr0 + qt * 16 + lrow) * N_QKV
                                          + ks * 32 + lk8);

    bf16x8 ones8;
#pragma unroll
    for (int e = 0; e < 8; ++e) ones8[e] = (bf16)1.0f;

    const f32x4 zf = {0.f, 0.f, 0.f, 0.f};

    f32x4 o[2][4] = {};
    f32x4 o4[2] = {};

    const int srow = wave * 16 + (lane >> 2);
    const int scol = (lane & 3) * 8;
    const bf16* kg = Kp + (size_t)srow * N_QKV + scol;
    const int vsrow = qg * 16 + (lane >> 2);
    const bf16* vg = Vtp + (size_t)vsrow * SEQ + jp * 32 + scol;
    const int kwo = wave * 512;

    gll16(kg,      &Ks[0][0][0] + kwo);
    gll16(kg + 32, &Ks[0][1][0] + kwo);
    gll16(vg,      &Vs[0][0][0] + kwo);
    gll16(vg + 64, &Vs[0][2][0] + kwo);
    kg += (size_t)128 * N_QKV;
    vg += 128;

    for (int jt = 0; jt < SEQ / 128; ++jt) {
        const int cur = jt & 1;
        __syncthreads();

        if (jt + 1 < SEQ / 128) {
            const int nxt = cur ^ 1;
            gll16(kg,      &Ks[nxt][0][0] + kwo);
            gll16(kg + 32, &Ks[nxt][1][0] + kwo);
            gll16(vg,      &Vs[nxt][0][0] + kwo);
            gll16(vg + 64, &Vs[nxt][2][0] + kwo);
            kg += (size_t)128 * N_QKV;
            vg += 128;
        }

#pragma unroll
        for (int pp = 0; pp < 2; ++pp) {
            const int p = (pp << 1) | jp;
            f32x4 Sp[2][2];
            __builtin_amdgcn_s_setprio(1);
#pragma unroll
            for (int m = 0; m < 2; ++m) {
                const int jn = 2 * p + m;
                bf16x8 kb0 = *(const bf16x8*)&Ks[cur][0][(jn * 16 + lrow) * 32 + lk8];
                bf16x8 kb1 = *(const bf16x8*)&Ks[cur][1][(jn * 16 + lrow) * 32 + lk8];
                Sp[m][0] = MFMA16(kb0, qf[0][0], zf);
                Sp[m][0] = MFMA16(kb1, qf[0][1], Sp[m][0]);
                Sp[m][1] = MFMA16(kb0, qf[1][0], zf);
                Sp[m][1] = MFMA16(kb1, qf[1][1], Sp[m][1]);
            }
            __builtin_amdgcn_s_setprio(0);

            union { bf16x8 v; uint32_t d[4]; } pb[2];
#pragma unroll
            for (int qt = 0; qt < 2; ++qt) {
                const f32x4 s0 = Sp[0][qt];
                const f32x4 s1 = Sp[1][qt];
                pb[qt].d[0] = pk2(__builtin_amdgcn_exp2f(s0[0]),
                                  __builtin_amdgcn_exp2f(s0[1]));
                pb[qt].d[1] = pk2(__builtin_amdgcn_exp2f(s0[2]),
                                  __builtin_amdgcn_exp2f(s0[3]));
                pb[qt].d[2] = pk2(__builtin_amdgcn_exp2f(s1[0]),
                                  __builtin_amdgcn_exp2f(s1[1]));
                pb[qt].d[3] = pk2(__builtin_amdgcn_exp2f(s1[2]),
                                  __builtin_amdgcn_exp2f(s1[3]));
            }

            __builtin_amdgcn_s_setprio(1);
            o4[0] = MFMA16(ones8, pb[0].v, o4[0]);
            o4[1] = MFMA16(ones8, pb[1].v, o4[1]);
#pragma unroll
            for (int df = 0; df < 4; ++df) {
                bf16x8 vA = *(const bf16x8*)&Vs[cur][p][(df * 16 + lrow) * 32 + lk8];
                o[0][df] = MFMA16(vA, pb[0].v, o[0][df]);
                o[1][df] = MFMA16(vA, pb[1].v, o[1][df]);
            }
            __builtin_amdgcn_s_setprio(0);
        }
    }

    // combine j-parity partials through LDS (safe to overwrite Ks/Vs now)
    __syncthreads();
    float* shO = (float*)Ks;
    float* shS = (float*)Vs;
    if (jp == 1) {
#pragma unroll
        for (int qt = 0; qt < 2; ++qt)
#pragma unroll
            for (int df = 0; df < 4; ++df)
                *(f32x4*)&shO[((((qt * 4 + df) * 4) + qg) * 64 + lane) * 4] = o[qt][df];
        shS[(qg * 64 + lane) * 2 + 0] = o4[0][0];
        shS[(qg * 64 + lane) * 2 + 1] = o4[1][0];
    }
    __syncthreads();
    if (jp == 1) return;

#pragma unroll
    for (int qt = 0; qt < 2; ++qt)
#pragma unroll
        for (int df = 0; df < 4; ++df) {
            f32x4 t = *(const f32x4*)&shO[((((qt * 4 + df) * 4) + qg) * 64 + lane) * 4];
            o[qt][df][0] += t[0]; o[qt][df][1] += t[1];
            o[qt][df][2] += t[2]; o[qt][df][3] += t[3];
        }
    const float den0 = o4[0][0] + shS[(qg * 64 + lane) * 2 + 0];
    const float den1 = o4[1][0] + shS[(qg * 64 + lane) * 2 + 1];

#pragma unroll
    for (int qt = 0; qt < 2; ++qt) {
        const float inv = 1.0f / (qt ? den1 : den0);
        const int q = qr0 + qt * 16 + lrow;
#pragma unroll
        for (int df = 0; df < 4; ++df) {
            bf16x4 vv;
#pragma unroll
            for (int r = 0; r < 4; ++r)
                vv[r] = pack_bf16(o[qt][df][r] * inv);
            *(bf16x4*)&O[(size_t)(b * SEQ + q) * FDIM + h * HD + df * 16 + quad * 4] = vv;
        }
    }
}

// ---------------------------------------------------------------------------
extern "C" void kernel_launch(void* const* d_in, const int* in_sizes, int n_in,
                              void* d_out, int out_size, void* d_ws, size_t ws_size,
                              hipStream_t stream) {
    (void)in_sizes; (void)n_in; (void)out_size; (void)ws_size;
    const float* x  = (const float*)d_in[0];
    const float* Wq = (const float*)d_in[1];
    const float* bq = (const float*)d_in[2];
    const float* Wk = (const float*)d_in[3];
    const float* bk = (const float*)d_in[4];
    const float* Wv = (const float*)d_in[5];
    const float* bv = (const float*)d_in[6];
    const float* Wo = (const float*)d_in[7];
    const float* bo = (const float*)d_in[8];
    float* out = (float*)d_out;

    char* ws = (char*)d_ws;
    bf16* xb    = (bf16*)(ws);                // 8 MB; reused as Ob after GEMM1
    bf16* Wcat  = (bf16*)(ws + 8388608);      // 6 MB
    bf16* Wob   = (bf16*)(ws + 14680064);     // 2 MB
    float* bcat = (float*)(ws + 16777216);    // 12 KB
    bf16* QKV   = (bf16*)(ws + 16789504);     // 24 MB (V third unused)
    bf16* Vt    = (bf16*)(ws + 41955328);     // 8 MB, j-permuted layout
    bf16* Ob    = xb;                         // x no longer needed after GEMM1

    static bool s_attr_done = false;
    if (!s_attr_done) {
        (void)hipFuncSetAttribute(reinterpret_cast<const void*>(gemm256),
                                  hipFuncAttributeMaxDynamicSharedMemorySize,
                                  131072);
        s_attr_done = true;
    }

    convert_k<<<dim3(1024), dim3(256), 0, stream>>>(x, Wq, bq, Wk, bk, Wv, bv, Wo,
                                                    xb, Wcat, Wob, bcat);
    gemm256<<<dim3(N_QKV / 256, M_TOK / 256), dim3(512), 131072, stream>>>(
        xb, Wcat, bcat, QKV, Vt, M_TOK, N_QKV, FDIM);
    attn_k<<<dim3((SEQ / 128) * BB * NH), dim3(512), 0, stream>>>(QKV, Vt, Ob);
    gemm_bt<64><<<dim3(FDIM / 128, M_TOK / 64), dim3(256), 0, stream>>>(
        Ob, Wob, bo, out, M_TOK, FDIM, FDIM);
}